// Round 11
// baseline (138.194 us; speedup 1.0000x reference)
//
#include <hip/hip_runtime.h>

// R11 — DECOMPOSITION PROBE (regression expected; revert next round).
// Question: the real first output pass costs ~55-60us while a marginal
// (second) streaming pass costs only ~29us (R8). Is the extra ~30us
// (S) store-path/coherence cost of first-touch on post-fill MALL state
//     (dirty poison evictions — unfixable, ceiling), or
// (C) compute/latency structure (fixable)?
// Method: pass 0 = STORE-ONLY (stream zeros to every out address, vmcnt(0)
// drain), then the full real pass (R9 structure, streaming stores). Pass 0
// faces exactly the MALL state the real first pass normally faces.
// Readout: dur ~145-155 -> (S), stores dominate -> declare ceiling next.
//          dur ~118-126 -> (C), ~30us is compute-side -> keep attacking.

#define NC 91
#define TT 1600
#define T4 (TT / 4)         // 400 float4 columns
#define ROWS 16
#define RPAD 20             // padded row-dim: 80B stride, 16B-aligned
#define NTHREADS 448
#define TABN (ROWS * NC)    // 1456 logical floats
#define TAB4 (TABN / 4)     // 364 float4 loads in prologue

typedef float vfloat4 __attribute__((ext_vector_type(4)));

__device__ __forceinline__ float focal_tab(float x) {
    const float p = __builtin_amdgcn_rcpf(1.f + __expf(-x));  // sigmoid
    const float omp = 1.f - p;
    const float neg = 0.75f * p * p * (-__logf(omp + 1e-8f));
    const float pos = 0.25f * omp * omp * (-__logf(p + 1e-8f));
    return 2.f * (pos - neg) + 2.f;   // fold COST_CLASS and giou's "+1"
}

__device__ __forceinline__ void store_stream(vfloat4* addr, vfloat4 v) {
    asm volatile("global_store_dwordx4 %0, %1, off sc0 sc1 nt"
                 :: "v"(addr), "v"(v)
                 : "memory");
}

__global__ __launch_bounds__(NTHREADS, 4) void matcher_kernel(
    const float* __restrict__ logits,      // [N, 91]
    const float4* __restrict__ pboxes,     // [N] (cx,cy,w,h)
    const int4* __restrict__ tids,         // [T/4]
    const float4* __restrict__ tboxes,     // [T] (cx,cy,w,h)
    vfloat4* __restrict__ out)             // [N, T/4]
{
    __shared__ __align__(16) float tab_t[NC * RPAD];   // [class][row(padded)]

    const int n0 = blockIdx.x * ROWS;
    const int tid = threadIdx.x;
    const bool active = (tid < T4);

    // ===== PASS 0: STORE-ONLY probe — zeros to every out address =====
    // Faces the exact post-fill MALL state the real first pass would face.
    if (active) {
        vfloat4 z = 0.f;
#pragma unroll
        for (int r = 0; r < ROWS; ++r)
            store_stream(&out[(size_t)(n0 + r) * T4 + tid], z);
    }
    // full drain: make pass 0 a cleanly separated serial segment per wave
    asm volatile("s_waitcnt vmcnt(0)" ::: "memory");

    // ===== real kernel (R9 structure, streaming stores) =====
    int4 ids = {0, 0, 0, 0};
    float4 tb[4];
    if (active) {
        ids = tids[tid];
#pragma unroll
        for (int j = 0; j < 4; ++j) tb[j] = tboxes[tid * 4 + j];
    }

    if (tid < TAB4) {
        const float4 v = *reinterpret_cast<const float4*>(
            logits + (size_t)n0 * NC + 4 * (size_t)tid);
        const float vv[4] = {v.x, v.y, v.z, v.w};
#pragma unroll
        for (int k = 0; k < 4; ++k) {
            const int e = 4 * tid + k;      // flat [16][91] element
            const int r = e / NC;
            const int c = e - r * NC;
            tab_t[c * RPAD + r] = focal_tab(vv[k]);
        }
    }
    __syncthreads();

    if (!active) return;

    const int idv[4] = {ids.x, ids.y, ids.z, ids.w};
    float tx0[4], ty0[4], tx1[4], ty1[4];
#pragma unroll
    for (int j = 0; j < 4; ++j) {
        tx0[j] = tb[j].x - 0.5f * tb[j].z;
        ty0[j] = tb[j].y - 0.5f * tb[j].w;
        tx1[j] = tb[j].x + 0.5f * tb[j].z;
        ty1[j] = tb[j].y + 0.5f * tb[j].w;
    }

    // prefetch 4 row-invariant class columns: 16x ds_read_b128 -> 64 VGPRs
    vfloat4 tv[4][4];
#pragma unroll
    for (int j = 0; j < 4; ++j)
#pragma unroll
        for (int q = 0; q < 4; ++q)
            tv[j][q] = *reinterpret_cast<const vfloat4*>(
                &tab_t[idv[j] * RPAD + 4 * q]);

#pragma unroll
    for (int r = 0; r < ROWS; ++r) {
        const float4 b = pboxes[n0 + r];   // block-uniform -> s_load
        const float pcx = b.x, pcy = b.y, pw = b.z, ph = b.w;
        const float px0 = pcx - 0.5f * pw, py0 = pcy - 0.5f * ph;
        const float px1 = pcx + 0.5f * pw, py1 = pcy + 0.5f * ph;
        const float pa  = pw * ph;
        vfloat4 res;
#pragma unroll
        for (int j = 0; j < 4; ++j) {
            const float tw = tx1[j] - tx0[j];
            const float th = ty1[j] - ty0[j];
            const float iwr = fminf(px1, tx1[j]) - fmaxf(px0, tx0[j]);
            const float ihr = fminf(py1, ty1[j]) - fmaxf(py0, ty0[j]);
            const float inter = fmaxf(iwr, 0.f) * fmaxf(ihr, 0.f);
            const float uni = pa + tw * th - inter;
            const float ew = (pw + tw) - iwr;   // min+max identity
            const float eh = (ph + th) - ihr;
            const float ae = ew * eh;
            const float tcx = tx0[j] + 0.5f * tw;
            const float tcy = ty0[j] + 0.5f * th;
            const float l1 = fabsf(pcx - tcx) + fabsf(pcy - tcy)
                           + fabsf(pw - tw) + fabsf(ph - th);
            res[j] = 5.f * l1 + tv[j][r >> 2][r & 3]
                   - 2.f * inter * __builtin_amdgcn_rcpf(uni)
                   - 2.f * uni * __builtin_amdgcn_rcpf(ae);
        }
        store_stream(&out[(size_t)(n0 + r) * T4 + tid], res);
    }
}

extern "C" void kernel_launch(void* const* d_in, const int* in_sizes, int n_in,
                              void* d_out, int out_size, void* d_ws, size_t ws_size,
                              hipStream_t stream) {
    const float* logits  = (const float*)d_in[0];
    const float4* pboxes = (const float4*)d_in[1];
    const int4* tids     = (const int4*)d_in[2];
    const float4* tboxes = (const float4*)d_in[3];
    vfloat4* out = (vfloat4*)d_out;
    const int N = in_sizes[1] / 4;  // 14400 rows
    matcher_kernel<<<N / ROWS, NTHREADS, 0, stream>>>(logits, pboxes, tids, tboxes, out);
}

// Round 12
// 125.919 us; speedup vs baseline: 1.0975x; 1.0975x over previous
//
#include <hip/hip_runtime.h>

// HungarianMatcher cost matrix: C[n,t] = 5*L1(box_n,box_t) + 2*(pos-neg)[n,id_t] - 2*GIoU(n,t)
// bs=16, nq=900 -> N=14400 rows; T=1600 targets; nc=91 classes.
// R12: PHASE-SPLIT compute/store. R11's probe law: burst stores stream at
// 4.4-6.4 TB/s (store-only pass0 = 21us for 92MB, cold state, FETCH ~0 with
// sc0sc1nt), but compute-interleaved stores run ~1.6 TB/s (real pass ~58us,
// invariant to policy/occupancy/VALU/LDS across 12 variants). Each wave was
// emitting one isolated 1KB store every ~300cyc; fragmented arrival kills
// memory-side write combining. Fix: compute ALL 16 rows into res[16] regs
// (64 VGPR), then fire all 16 streaming stores back-to-back -> per-block
// ~100KB contiguous burst, pass0's exact shape.
// VGPR ~110 < 128 cap of (448,4); spill signature (+12us, R2) is the abort
// diagnostic. tab reads stay as in-loop LDS scalars (R9's VGPR=64 showed the
// compiler sank tv[] to LDS reads anyway — harmless).
// Predicted: matcher ~58 -> ~30-35, dur 120.5 -> ~95-103.

#define NC 91
#define TT 1600
#define T4 (TT / 4)         // 400 float4 columns
#define ROWS 16
#define RPAD 20             // padded row-dim: 80B stride, 16B-aligned
#define NTHREADS 448
#define TABN (ROWS * NC)    // 1456 logical floats
#define TAB4 (TABN / 4)     // 364 float4 loads in prologue

typedef float vfloat4 __attribute__((ext_vector_type(4)));

__device__ __forceinline__ float focal_tab(float x) {
    const float p = __builtin_amdgcn_rcpf(1.f + __expf(-x));  // sigmoid
    const float omp = 1.f - p;
    const float neg = 0.75f * p * p * (-__logf(omp + 1e-8f));
    const float pos = 0.25f * omp * omp * (-__logf(p + 1e-8f));
    return 2.f * (pos - neg) + 2.f;   // fold COST_CLASS and giou's "+1"
}

__device__ __forceinline__ void store_stream(vfloat4* addr, vfloat4 v) {
    // no-allocate streaming store (R11: FETCH 190MB -> 3MB vs plain)
    asm volatile("global_store_dwordx4 %0, %1, off sc0 sc1 nt"
                 :: "v"(addr), "v"(v)
                 : "memory");
}

__global__ __launch_bounds__(NTHREADS, 4) void matcher_kernel(
    const float* __restrict__ logits,      // [N, 91]
    const float4* __restrict__ pboxes,     // [N] (cx,cy,w,h)
    const int4* __restrict__ tids,         // [T/4]
    const float4* __restrict__ tboxes,     // [T] (cx,cy,w,h)
    vfloat4* __restrict__ out)             // [N, T/4]
{
    __shared__ __align__(16) float tab_t[NC * RPAD];   // [class][row(padded)]

    const int n0 = blockIdx.x * ROWS;
    const int tid = threadIdx.x;
    const bool active = (tid < T4);

    // --- issue t-side vector loads FIRST; latency hides under tab build ---
    int4 ids = {0, 0, 0, 0};
    float4 tb[4];
    if (active) {
        ids = tids[tid];
#pragma unroll
        for (int j = 0; j < 4; ++j) tb[j] = tboxes[tid * 4 + j];
    }

    // --- prologue: coalesced float4 logits -> focal -> transposed LDS ---
    if (tid < TAB4) {
        const float4 v = *reinterpret_cast<const float4*>(
            logits + (size_t)n0 * NC + 4 * (size_t)tid);
        const float vv[4] = {v.x, v.y, v.z, v.w};
#pragma unroll
        for (int k = 0; k < 4; ++k) {
            const int e = 4 * tid + k;      // flat [16][91] element
            const int r = e / NC;
            const int c = e - r * NC;
            tab_t[c * RPAD + r] = focal_tab(vv[k]);
        }
    }
    __syncthreads();

    if (!active) return;

    const int idv[4] = {ids.x, ids.y, ids.z, ids.w};
    float tx0[4], ty0[4], tx1[4], ty1[4];
#pragma unroll
    for (int j = 0; j < 4; ++j) {
        tx0[j] = tb[j].x - 0.5f * tb[j].z;
        ty0[j] = tb[j].y - 0.5f * tb[j].w;
        tx1[j] = tb[j].x + 0.5f * tb[j].z;
        ty1[j] = tb[j].y + 0.5f * tb[j].w;
    }

    // ===== PHASE 1: compute ALL rows into registers (no stores) =====
    vfloat4 res[ROWS];
#pragma unroll
    for (int r = 0; r < ROWS; ++r) {
        const float4 b = pboxes[n0 + r];   // block-uniform -> s_load
        const float pcx = b.x, pcy = b.y, pw = b.z, ph = b.w;
        const float px0 = pcx - 0.5f * pw, py0 = pcy - 0.5f * ph;
        const float px1 = pcx + 0.5f * pw, py1 = pcy + 0.5f * ph;
        const float pa  = pw * ph;
#pragma unroll
        for (int j = 0; j < 4; ++j) {
            const float tw = tx1[j] - tx0[j];
            const float th = ty1[j] - ty0[j];
            const float iwr = fminf(px1, tx1[j]) - fmaxf(px0, tx0[j]);
            const float ihr = fminf(py1, ty1[j]) - fmaxf(py0, ty0[j]);
            const float inter = fmaxf(iwr, 0.f) * fmaxf(ihr, 0.f);
            const float uni = pa + tw * th - inter;
            const float ew = (pw + tw) - iwr;   // min+max identity
            const float eh = (ph + th) - ihr;
            const float ae = ew * eh;
            const float tcx = tx0[j] + 0.5f * tw;
            const float tcy = ty0[j] + 0.5f * th;
            const float l1 = fabsf(pcx - tcx) + fabsf(pcy - tcy)
                           + fabsf(pw - tw) + fabsf(ph - th);
            res[r][j] = 5.f * l1 + tab_t[idv[j] * RPAD + r]
                      - 2.f * inter * __builtin_amdgcn_rcpf(uni)
                      - 2.f * uni * __builtin_amdgcn_rcpf(ae);
        }
    }

    // ===== PHASE 2: burst all 16 stores back-to-back =====
    // Per row: threads 0-399 cover 6400B contiguous; 16 rows = the block's
    // whole 100KB tile arrives as one burst (pass0's proven-fast shape).
#pragma unroll
    for (int r = 0; r < ROWS; ++r)
        store_stream(&out[(size_t)(n0 + r) * T4 + tid], res[r]);
}

extern "C" void kernel_launch(void* const* d_in, const int* in_sizes, int n_in,
                              void* d_out, int out_size, void* d_ws, size_t ws_size,
                              hipStream_t stream) {
    const float* logits  = (const float*)d_in[0];
    const float4* pboxes = (const float4*)d_in[1];
    const int4* tids     = (const int4*)d_in[2];
    const float4* tboxes = (const float4*)d_in[3];
    vfloat4* out = (vfloat4*)d_out;
    const int N = in_sizes[1] / 4;  // 14400 rows
    matcher_kernel<<<N / ROWS, NTHREADS, 0, stream>>>(logits, pboxes, tids, tboxes, out);
}

// Round 13
// 120.371 us; speedup vs baseline: 1.1481x; 1.0461x over previous
//
#include <hip/hip_runtime.h>

// HungarianMatcher cost matrix: C[n,t] = 5*L1(box_n,box_t) + 2*(pos-neg)[n,id_t] - 2*GIoU(n,t)
// bs=16, nq=900 -> N=14400 rows; T=1600 targets; nc=91 classes.
// R13: strength-reduction on the R9 champion (120.5us). All structural axes
// measured neutral (store policy x3, burst shape, TLP 6300 vs 12600 waves,
// blocks/CU, persistence, LDS-gather, prologue); per-pass VALU-busy ~11us,
// streaming-store pass ~21-29us. Last isolated lever: arithmetic count.
//  1) single-rcp GIoU: -2*inter/uni - 2*uni/ae == -2*(inter*ae + uni^2)/(uni*ae)
//     -> 1 rcp (trans) + ~same VALU, halves trans-pipe traffic.
//  2) revert R2's register diet: precompute per-j tw/th/ta/tcx/tcy (never rolled
//     back) -> ~5 VALU/elem saved; ~35 -> ~29 VALU/elem total.
//  3) tab read: per-j base VGPR (idv[j]*RPAD*4), unrolled r folds to ds_read
//     offset immediate -> zero per-read address math.
// Plain stores (champion config; policy proven neutral), ROWS=16, (448,4).
// Predicted: dur 120.5 -> ~114-117 if compute-wall tracks issue count;
// neutral -> declare ceiling next round with the full evidence chain.

#define NC 91
#define TT 1600
#define T4 (TT / 4)         // 400 float4 columns
#define ROWS 16
#define RPAD 20             // padded row-dim: 80B stride, 16B-aligned
#define NTHREADS 448
#define TABN (ROWS * NC)    // 1456 logical floats
#define TAB4 (TABN / 4)     // 364 float4 loads in prologue

typedef float vfloat4 __attribute__((ext_vector_type(4)));

__device__ __forceinline__ float focal_tab(float x) {
    const float p = __builtin_amdgcn_rcpf(1.f + __expf(-x));  // sigmoid
    const float omp = 1.f - p;
    const float neg = 0.75f * p * p * (-__logf(omp + 1e-8f));
    const float pos = 0.25f * omp * omp * (-__logf(p + 1e-8f));
    return 2.f * (pos - neg) + 2.f;   // fold COST_CLASS and giou's "+1"
}

__global__ __launch_bounds__(NTHREADS, 4) void matcher_kernel(
    const float* __restrict__ logits,      // [N, 91]
    const float4* __restrict__ pboxes,     // [N] (cx,cy,w,h)
    const int4* __restrict__ tids,         // [T/4]
    const float4* __restrict__ tboxes,     // [T] (cx,cy,w,h)
    vfloat4* __restrict__ out)             // [N, T/4]
{
    __shared__ __align__(16) float tab_t[NC * RPAD];   // [class][row(padded)]

    const int n0 = blockIdx.x * ROWS;
    const int tid = threadIdx.x;
    const bool active = (tid < T4);

    // --- issue t-side vector loads FIRST; latency hides under tab build ---
    int4 ids = {0, 0, 0, 0};
    float4 tb[4];
    if (active) {
        ids = tids[tid];
#pragma unroll
        for (int j = 0; j < 4; ++j) tb[j] = tboxes[tid * 4 + j];
    }

    // --- prologue: coalesced float4 logits -> focal -> transposed LDS ---
    if (tid < TAB4) {
        const float4 v = *reinterpret_cast<const float4*>(
            logits + (size_t)n0 * NC + 4 * (size_t)tid);
        const float vv[4] = {v.x, v.y, v.z, v.w};
#pragma unroll
        for (int k = 0; k < 4; ++k) {
            const int e = 4 * tid + k;      // flat [16][91] element
            const int r = e / NC;
            const int c = e - r * NC;
            tab_t[c * RPAD + r] = focal_tab(vv[k]);
        }
    }
    __syncthreads();

    if (!active) return;

    // full per-target state (diet reverted: +20 VGPR, -5 VALU/elem)
    float tx0[4], ty0[4], tx1[4], ty1[4];
    float tw[4], th[4], ta[4], tcx[4], tcy[4];
    const float* tbase[4];                  // per-j LDS base: &tab_t[id*RPAD]
    const int idv[4] = {ids.x, ids.y, ids.z, ids.w};
#pragma unroll
    for (int j = 0; j < 4; ++j) {
        tcx[j] = tb[j].x; tcy[j] = tb[j].y;
        tw[j]  = tb[j].z; th[j]  = tb[j].w;
        tx0[j] = tcx[j] - 0.5f * tw[j];
        ty0[j] = tcy[j] - 0.5f * th[j];
        tx1[j] = tcx[j] + 0.5f * tw[j];
        ty1[j] = tcy[j] + 0.5f * th[j];
        ta[j]  = tw[j] * th[j];
        tbase[j] = &tab_t[idv[j] * RPAD];   // unrolled r folds to offset:4r
    }

#pragma unroll
    for (int r = 0; r < ROWS; ++r) {
        // block-uniform address -> scalar load, lives in SGPRs (no VGPR cost)
        const float4 b = pboxes[n0 + r];
        const float pcx = b.x, pcy = b.y, pw = b.z, ph = b.w;
        const float px0 = pcx - 0.5f * pw, py0 = pcy - 0.5f * ph;
        const float px1 = pcx + 0.5f * pw, py1 = pcy + 0.5f * ph;
        const float pa  = pw * ph;
        vfloat4 res;
#pragma unroll
        for (int j = 0; j < 4; ++j) {
            // intersection (raw, may be negative)
            const float iwr = fminf(px1, tx1[j]) - fmaxf(px0, tx0[j]);
            const float ihr = fminf(py1, ty1[j]) - fmaxf(py0, ty0[j]);
            const float inter = fmaxf(iwr, 0.f) * fmaxf(ihr, 0.f);
            const float uni = pa + ta[j] - inter;
            // enclosing box via min+max identity (clamp is a no-op: w,h>=0)
            const float ew = (pw + tw[j]) - iwr;
            const float eh = (ph + th[j]) - ihr;
            const float ae = ew * eh;
            const float l1 = fabsf(pcx - tcx[j]) + fabsf(pcy - tcy[j])
                           + fabsf(pw - tw[j]) + fabsf(ph - th[j]);
            // single-rcp GIoU: -2*inter/uni - 2*uni/ae
            //   == -2*(inter*ae + uni*uni) / (uni*ae)
            const float num = __builtin_fmaf(uni, uni, inter * ae);
            const float q   = num * __builtin_amdgcn_rcpf(uni * ae);
            const float base = __builtin_fmaf(5.f, l1, tbase[j][r]);
            res[j] = __builtin_fmaf(-2.f, q, base);
        }
        out[(size_t)(n0 + r) * T4 + tid] = res;   // plain store (champion)
    }
}

extern "C" void kernel_launch(void* const* d_in, const int* in_sizes, int n_in,
                              void* d_out, int out_size, void* d_ws, size_t ws_size,
                              hipStream_t stream) {
    const float* logits  = (const float*)d_in[0];
    const float4* pboxes = (const float4*)d_in[1];
    const int4* tids     = (const int4*)d_in[2];
    const float4* tboxes = (const float4*)d_in[3];
    vfloat4* out = (vfloat4*)d_out;
    const int N = in_sizes[1] / 4;  // 14400 rows
    matcher_kernel<<<N / ROWS, NTHREADS, 0, stream>>>(logits, pboxes, tids, tboxes, out);
}

// Round 14
// 119.644 us; speedup vs baseline: 1.1550x; 1.0061x over previous
//
#include <hip/hip_runtime.h>

// HungarianMatcher cost matrix: C[n,t] = 5*L1(box_n,box_t) + 2*(pos-neg)[n,id_t] - 2*GIoU(n,t)
// bs=16, nq=900 -> N=14400 rows; T=1600 targets; nc=91 classes.
// R14: single-variable change on the R13 champion (120.37us): RPAD 20 -> 21.
// Evidence: R6/R11 counters show ~1.0-1.2M SQ_LDS_BANK_CONFLICT per pass.
// With RPAD=20, bank(id*20+r) mod 32 spans only 8 banks (gcd(20,32)=4) ->
// ~8-way conflict on all 64 scalar tab gathers/thread. gcd(21,32)=1 spreads
// random-id gathers across all 32 banks (~2-way = free). R13 reads the tab
// scalar-only, so the 16B-alignment RPAD=20 bought is no longer needed.
// Everything else byte-identical to R13 (single-rcp GIoU, full t-state,
// per-j tbase, plain stores, ROWS=16, (448,4)).
// Predicted: dur 120.4 -> ~116-118 if conflicts are on the critical path;
// neutral -> all counter-named mechanisms exhausted -> declare plateau.

#define NC 91
#define TT 1600
#define T4 (TT / 4)         // 400 float4 columns
#define ROWS 16
#define RPAD 21             // gcd(21,32)=1: gathers spread over all 32 banks
#define NTHREADS 448
#define TABN (ROWS * NC)    // 1456 logical floats
#define TAB4 (TABN / 4)     // 364 float4 loads in prologue

typedef float vfloat4 __attribute__((ext_vector_type(4)));

__device__ __forceinline__ float focal_tab(float x) {
    const float p = __builtin_amdgcn_rcpf(1.f + __expf(-x));  // sigmoid
    const float omp = 1.f - p;
    const float neg = 0.75f * p * p * (-__logf(omp + 1e-8f));
    const float pos = 0.25f * omp * omp * (-__logf(p + 1e-8f));
    return 2.f * (pos - neg) + 2.f;   // fold COST_CLASS and giou's "+1"
}

__global__ __launch_bounds__(NTHREADS, 4) void matcher_kernel(
    const float* __restrict__ logits,      // [N, 91]
    const float4* __restrict__ pboxes,     // [N] (cx,cy,w,h)
    const int4* __restrict__ tids,         // [T/4]
    const float4* __restrict__ tboxes,     // [T] (cx,cy,w,h)
    vfloat4* __restrict__ out)             // [N, T/4]
{
    __shared__ float tab_t[NC * RPAD];     // [class][row(padded, odd stride)]

    const int n0 = blockIdx.x * ROWS;
    const int tid = threadIdx.x;
    const bool active = (tid < T4);

    // --- issue t-side vector loads FIRST; latency hides under tab build ---
    int4 ids = {0, 0, 0, 0};
    float4 tb[4];
    if (active) {
        ids = tids[tid];
#pragma unroll
        for (int j = 0; j < 4; ++j) tb[j] = tboxes[tid * 4 + j];
    }

    // --- prologue: coalesced float4 logits -> focal -> transposed LDS ---
    if (tid < TAB4) {
        const float4 v = *reinterpret_cast<const float4*>(
            logits + (size_t)n0 * NC + 4 * (size_t)tid);
        const float vv[4] = {v.x, v.y, v.z, v.w};
#pragma unroll
        for (int k = 0; k < 4; ++k) {
            const int e = 4 * tid + k;      // flat [16][91] element
            const int r = e / NC;
            const int c = e - r * NC;
            tab_t[c * RPAD + r] = focal_tab(vv[k]);
        }
    }
    __syncthreads();

    if (!active) return;

    // full per-target state (R13: -5 VALU/elem vs diet)
    float tx0[4], ty0[4], tx1[4], ty1[4];
    float tw[4], th[4], ta[4], tcx[4], tcy[4];
    const float* tbase[4];                  // per-j LDS base: &tab_t[id*RPAD]
    const int idv[4] = {ids.x, ids.y, ids.z, ids.w};
#pragma unroll
    for (int j = 0; j < 4; ++j) {
        tcx[j] = tb[j].x; tcy[j] = tb[j].y;
        tw[j]  = tb[j].z; th[j]  = tb[j].w;
        tx0[j] = tcx[j] - 0.5f * tw[j];
        ty0[j] = tcy[j] - 0.5f * th[j];
        tx1[j] = tcx[j] + 0.5f * tw[j];
        ty1[j] = tcy[j] + 0.5f * th[j];
        ta[j]  = tw[j] * th[j];
        tbase[j] = &tab_t[idv[j] * RPAD];   // unrolled r folds to offset:4r
    }

#pragma unroll
    for (int r = 0; r < ROWS; ++r) {
        // block-uniform address -> scalar load, lives in SGPRs (no VGPR cost)
        const float4 b = pboxes[n0 + r];
        const float pcx = b.x, pcy = b.y, pw = b.z, ph = b.w;
        const float px0 = pcx - 0.5f * pw, py0 = pcy - 0.5f * ph;
        const float px1 = pcx + 0.5f * pw, py1 = pcy + 0.5f * ph;
        const float pa  = pw * ph;
        vfloat4 res;
#pragma unroll
        for (int j = 0; j < 4; ++j) {
            // intersection (raw, may be negative)
            const float iwr = fminf(px1, tx1[j]) - fmaxf(px0, tx0[j]);
            const float ihr = fminf(py1, ty1[j]) - fmaxf(py0, ty0[j]);
            const float inter = fmaxf(iwr, 0.f) * fmaxf(ihr, 0.f);
            const float uni = pa + ta[j] - inter;
            // enclosing box via min+max identity (clamp is a no-op: w,h>=0)
            const float ew = (pw + tw[j]) - iwr;
            const float eh = (ph + th[j]) - ihr;
            const float ae = ew * eh;
            const float l1 = fabsf(pcx - tcx[j]) + fabsf(pcy - tcy[j])
                           + fabsf(pw - tw[j]) + fabsf(ph - th[j]);
            // single-rcp GIoU: -2*inter/uni - 2*uni/ae
            //   == -2*(inter*ae + uni*uni) / (uni*ae)
            const float num = __builtin_fmaf(uni, uni, inter * ae);
            const float q   = num * __builtin_amdgcn_rcpf(uni * ae);
            const float base = __builtin_fmaf(5.f, l1, tbase[j][r]);
            res[j] = __builtin_fmaf(-2.f, q, base);
        }
        out[(size_t)(n0 + r) * T4 + tid] = res;   // plain store (champion)
    }
}

extern "C" void kernel_launch(void* const* d_in, const int* in_sizes, int n_in,
                              void* d_out, int out_size, void* d_ws, size_t ws_size,
                              hipStream_t stream) {
    const float* logits  = (const float*)d_in[0];
    const float4* pboxes = (const float4*)d_in[1];
    const int4* tids     = (const int4*)d_in[2];
    const float4* tboxes = (const float4*)d_in[3];
    vfloat4* out = (vfloat4*)d_out;
    const int N = in_sizes[1] / 4;  // 14400 rows
    matcher_kernel<<<N / ROWS, NTHREADS, 0, stream>>>(logits, pboxes, tids, tboxes, out);
}